// Round 1
// baseline (25.855 us; speedup 1.0000x reference)
//
#include <hip/hip_runtime.h>
#include <math.h>

#define DQ 512          // input feature dim
#define NQ 4            // qubits
#define LQ 2            // layers
#define ROWS_PER_BLOCK 64
#define BLOCK 256

__global__ __launch_bounds__(BLOCK) void qrnn_kernel(
    const float* __restrict__ inputs,   // (B,512)
    const float* __restrict__ prev_h,   // (B,4)
    const float* __restrict__ W_enc,    // (516,4)
    const float* __restrict__ b_enc,    // (4)
    const float* __restrict__ theta,    // (2,4,3)
    const float* __restrict__ W_out,    // (4,4)
    const float* __restrict__ b_out,    // (4)
    float* __restrict__ out,            // (B,4)
    int B)
{
    __shared__ float4 sSum[ROWS_PER_BLOCK];   // raw input-part dot products per row
    __shared__ float  sU[LQ * NQ * 8];        // 8 unitaries, 2x2 complex each

    const int tid  = threadIdx.x;
    const int lane = tid & 63;
    const int wave = tid >> 6;
    const int blockBase = blockIdx.x * ROWS_PER_BLOCK;

    // ---------------- Phase 0: shared unitaries U = RY * RZ * RX ----------------
    if (tid < LQ * NQ) {
        const int l = tid >> 2, q = tid & 3;
        const float a  = theta[(l * NQ + q) * 3 + 0] * 0.5f;
        const float b  = theta[(l * NQ + q) * 3 + 1] * 0.5f;
        const float cc = theta[(l * NQ + q) * 3 + 2] * 0.5f;
        float sa, ca, sb, cb, sy, cy;
        sincosf(a,  &sa, &ca);
        sincosf(b,  &sb, &cb);
        sincosf(cc, &sy, &cy);
        // M = RZ * RX
        const float m00r =  ca * cb, m00i = -ca * sb;
        const float m01r = -sa * sb, m01i = -sa * cb;
        const float m10r =  sa * sb, m10i = -sa * cb;
        const float m11r =  ca * cb, m11i =  ca * sb;
        // U = RY * M,  RY = [[cy,-sy],[sy,cy]] (real)
        float* u = &sU[tid * 8];
        u[0] = cy * m00r - sy * m10r;  u[1] = cy * m00i - sy * m10i;  // U00
        u[2] = cy * m01r - sy * m11r;  u[3] = cy * m01i - sy * m11i;  // U01
        u[4] = sy * m00r + cy * m10r;  u[5] = sy * m00i + cy * m10i;  // U10
        u[6] = sy * m01r + cy * m11r;  u[7] = sy * m01i + cy * m11i;  // U11
    }

    // ---------------- Phase 1: encoding matmul (inputs part) ----------------
    // Lane l owns feature columns d = 4l..4l+3 and d = 256+4l..+3.
    // W_enc rows for those d are lane-invariant across rows: hoist into registers.
    const float4* __restrict__ W4 = (const float4*)W_enc;   // W4[d] = W_enc[d][0..3]
    float4 wreg[8];
#pragma unroll
    for (int k = 0; k < 4; ++k) {
        wreg[k]     = W4[4 * lane + k];
        wreg[k + 4] = W4[256 + 4 * lane + k];
    }

    const int r0 = wave * 16;
    // prefetch first row
    float4 x0, x1;
    {
        const int row = blockBase + r0;
        const float4* in4 = (const float4*)(inputs + (size_t)row * DQ);
        x0 = in4[lane];
        x1 = in4[lane + 64];
    }

    for (int r = r0; r < r0 + 16; ++r) {
        // prefetch next row while computing this one
        float4 n0, n1;
        if (r + 1 < r0 + 16) {
            const int nrow = blockBase + r + 1;
            const float4* in4 = (const float4*)(inputs + (size_t)nrow * DQ);
            n0 = in4[lane];
            n1 = in4[lane + 64];
        }

        float xs[8] = { x0.x, x0.y, x0.z, x0.w, x1.x, x1.y, x1.z, x1.w };
        float4 acc = make_float4(0.f, 0.f, 0.f, 0.f);
#pragma unroll
        for (int k = 0; k < 8; ++k) {
            acc.x += xs[k] * wreg[k].x;
            acc.y += xs[k] * wreg[k].y;
            acc.z += xs[k] * wreg[k].z;
            acc.w += xs[k] * wreg[k].w;
        }
        // butterfly reduce across 64 lanes
#pragma unroll
        for (int off = 32; off > 0; off >>= 1) {
            acc.x += __shfl_xor(acc.x, off);
            acc.y += __shfl_xor(acc.y, off);
            acc.z += __shfl_xor(acc.z, off);
            acc.w += __shfl_xor(acc.w, off);
        }
        if (lane == 0) sSum[r] = acc;

        x0 = n0; x1 = n1;
    }

    __syncthreads();

    // ---------------- Phase 2: per-row circuit (wave 0, one lane per row) ----------------
    if (tid < ROWS_PER_BLOCK) {
        const int row = blockBase + tid;
        float4 sum = sSum[tid];
        float s[4] = { sum.x, sum.y, sum.z, sum.w };

        // prev_h part of the encoding matmul + bias
        const float4 ph = *(const float4*)(prev_h + (size_t)row * 4);
        const float pk[4] = { ph.x, ph.y, ph.z, ph.w };
#pragma unroll
        for (int k = 0; k < 4; ++k) {
            const float4 wr = W4[512 + k];
            s[0] += pk[k] * wr.x;
            s[1] += pk[k] * wr.y;
            s[2] += pk[k] * wr.z;
            s[3] += pk[k] * wr.w;
        }
#pragma unroll
        for (int j = 0; j < 4; ++j) s[j] += b_enc[j];

        // half-angles: h = tanh(s) * pi/2; initial separable state amplitudes
        float cq[4], sq[4];
#pragma unroll
        for (int j = 0; j < 4; ++j) {
            const float h = tanhf(s[j]) * 1.57079632679489662f;
            __sincosf(h, &sq[j], &cq[j]);
        }

        float ar[16], ai[16];
#pragma unroll
        for (int j = 0; j < 16; ++j) {
            float v = ((j >> 3) & 1) ? sq[0] : cq[0];
            v      *= ((j >> 2) & 1) ? sq[1] : cq[1];
            v      *= ((j >> 1) & 1) ? sq[2] : cq[2];
            v      *= ((j >> 0) & 1) ? sq[3] : cq[3];
            ar[j] = v;
            ai[j] = 0.f;
        }

        // layers
#pragma unroll
        for (int l = 0; l < LQ; ++l) {
#pragma unroll
            for (int q = 0; q < NQ; ++q) {
                const float* u = &sU[(l * NQ + q) * 8];
                const float u00r = u[0], u00i = u[1], u01r = u[2], u01i = u[3];
                const float u10r = u[4], u10i = u[5], u11r = u[6], u11i = u[7];
                const int bit = 1 << (3 - q);
#pragma unroll
                for (int j = 0; j < 16; ++j) {
                    if (j & bit) continue;          // compile-time resolved
                    const int k = j | bit;
                    const float a0r = ar[j], a0i = ai[j];
                    const float a1r = ar[k], a1i = ai[k];
                    ar[j] = u00r * a0r - u00i * a0i + u01r * a1r - u01i * a1i;
                    ai[j] = u00r * a0i + u00i * a0r + u01r * a1i + u01i * a1r;
                    ar[k] = u10r * a0r - u10i * a0i + u11r * a1r - u11i * a1i;
                    ai[k] = u10r * a0i + u10i * a0r + u11r * a1i + u11i * a1r;
                }
            }
            // CNOT chain: control q, target q+1
#pragma unroll
            for (int q = 0; q < NQ - 1; ++q) {
                const int cb = 1 << (3 - q), tb = 1 << (2 - q);
#pragma unroll
                for (int j = 0; j < 16; ++j) {
                    if ((j & cb) && !(j & tb)) {    // compile-time resolved
                        const int k = j | tb;
                        float t;
                        t = ar[j]; ar[j] = ar[k]; ar[k] = t;
                        t = ai[j]; ai[j] = ai[k]; ai[k] = t;
                    }
                }
            }
        }

        // PauliZ expectations
        float ev[4] = { 0.f, 0.f, 0.f, 0.f };
#pragma unroll
        for (int j = 0; j < 16; ++j) {
            const float p = ar[j] * ar[j] + ai[j] * ai[j];
#pragma unroll
            for (int q = 0; q < 4; ++q)
                ev[q] += (j & (1 << (3 - q))) ? -p : p;
        }

        // output layer
        float ob[4];
#pragma unroll
        for (int j = 0; j < 4; ++j) {
            float t = b_out[j];
#pragma unroll
            for (int q = 0; q < 4; ++q) t += ev[q] * W_out[q * 4 + j];
            ob[j] = tanhf(t);
        }
        *(float4*)(out + (size_t)row * 4) = make_float4(ob[0], ob[1], ob[2], ob[3]);
    }
}

extern "C" void kernel_launch(void* const* d_in, const int* in_sizes, int n_in,
                              void* d_out, int out_size, void* d_ws, size_t ws_size,
                              hipStream_t stream) {
    const float* inputs = (const float*)d_in[0];
    const float* prev_h = (const float*)d_in[1];
    const float* W_enc  = (const float*)d_in[2];
    const float* b_enc  = (const float*)d_in[3];
    const float* theta  = (const float*)d_in[4];
    const float* W_out  = (const float*)d_in[5];
    const float* b_out  = (const float*)d_in[6];
    float* out = (float*)d_out;

    const int B = in_sizes[0] / DQ;                 // 32768
    const int grid = (B + ROWS_PER_BLOCK - 1) / ROWS_PER_BLOCK;  // 512

    qrnn_kernel<<<grid, BLOCK, 0, stream>>>(inputs, prev_h, W_enc, b_enc, theta,
                                            W_out, b_out, out, B);
}

// Round 2
// 21.548 us; speedup vs baseline: 1.1999x; 1.1999x over previous
//
#include <hip/hip_runtime.h>
#include <math.h>

#define DQ 512          // input feature dim
#define NQ 4            // qubits
#define LQ 2            // layers
#define RPB 64          // rows per block
#define BLOCK 256

// Sum across the 16-lane DPP "row" group via 4 row_ror steps (pure VALU, no LDS pipe).
// After this every lane holds the sum of its 16-lane group.
__device__ __forceinline__ float rowsum16(float v) {
    int x;
    x = __builtin_amdgcn_update_dpp(0, __float_as_int(v), 0x121, 0xF, 0xF, true); // ror:1
    v += __int_as_float(x);
    x = __builtin_amdgcn_update_dpp(0, __float_as_int(v), 0x122, 0xF, 0xF, true); // ror:2
    v += __int_as_float(x);
    x = __builtin_amdgcn_update_dpp(0, __float_as_int(v), 0x124, 0xF, 0xF, true); // ror:4
    v += __int_as_float(x);
    x = __builtin_amdgcn_update_dpp(0, __float_as_int(v), 0x128, 0xF, 0xF, true); // ror:8
    v += __int_as_float(x);
    return v;
}

__global__ __launch_bounds__(BLOCK) void qrnn_kernel(
    const float* __restrict__ inputs,   // (B,512)
    const float* __restrict__ prev_h,   // (B,4)
    const float* __restrict__ W_enc,    // (516,4)
    const float* __restrict__ b_enc,    // (4)
    const float* __restrict__ theta,    // (2,4,3)
    const float* __restrict__ W_out,    // (4,4)
    const float* __restrict__ b_out,    // (4)
    float* __restrict__ out,            // (B,4)
    int B)
{
    __shared__ float4 sPart[RPB][5];       // 4 group-partials per row (padded stride 20 dwords)
    __shared__ float  sC[RPB * 5];         // cos(half-angle) per (row,comp), stride 5
    __shared__ float  sS[RPB * 5];         // sin(half-angle)
    __shared__ float  sU[LQ * NQ * 8];     // 8 unitaries, 2x2 complex each

    const int tid  = threadIdx.x;
    const int lane = tid & 63;
    const int wave = tid >> 6;
    const int blockBase = blockIdx.x * RPB;

    // ---------------- Phase 0: shared unitaries U = RY * RZ * RX ----------------
    if (tid < LQ * NQ) {
        const int l = tid >> 2, q = tid & 3;
        const float a  = theta[(l * NQ + q) * 3 + 0] * 0.5f;
        const float b  = theta[(l * NQ + q) * 3 + 1] * 0.5f;
        const float cc = theta[(l * NQ + q) * 3 + 2] * 0.5f;
        float sa, ca, sb, cb, sy, cy;
        sincosf(a,  &sa, &ca);
        sincosf(b,  &sb, &cb);
        sincosf(cc, &sy, &cy);
        const float m00r =  ca * cb, m00i = -ca * sb;
        const float m01r = -sa * sb, m01i = -sa * cb;
        const float m10r =  sa * sb, m10i = -sa * cb;
        const float m11r =  ca * cb, m11i =  ca * sb;
        float* u = &sU[tid * 8];
        u[0] = cy * m00r - sy * m10r;  u[1] = cy * m00i - sy * m10i;  // U00
        u[2] = cy * m01r - sy * m11r;  u[3] = cy * m01i - sy * m11i;  // U01
        u[4] = sy * m00r + cy * m10r;  u[5] = sy * m00i + cy * m10i;  // U10
        u[6] = sy * m01r + cy * m11r;  u[7] = sy * m01i + cy * m11i;  // U11
    }

    // ---------------- Phase 1a: encoding matmul, inputs part ----------------
    const float4* __restrict__ W4 = (const float4*)W_enc;   // W4[d] = W_enc[d][0..3]
    float4 wreg[8];
#pragma unroll
    for (int k = 0; k < 4; ++k) {
        wreg[k]     = W4[4 * lane + k];
        wreg[k + 4] = W4[256 + 4 * lane + k];
    }

    const int r0 = wave * 16;
    const float4* __restrict__ inBase = (const float4*)inputs;

    // 4-deep software pipeline: rows r+1..r+4 in flight while computing row r
    float4 xb[4][2];
#pragma unroll
    for (int p = 0; p < 4; ++p) {
        const float4* in4 = inBase + (size_t)(blockBase + r0 + p) * (DQ / 4);
        xb[p][0] = in4[lane];
        xb[p][1] = in4[lane + 64];
    }

#pragma unroll
    for (int r = 0; r < 16; ++r) {
        const int slot = r & 3;                 // static after full unroll
        const float4 x0 = xb[slot][0];
        const float4 x1 = xb[slot][1];
        if (r + 4 < 16) {
            const float4* in4 = inBase + (size_t)(blockBase + r0 + r + 4) * (DQ / 4);
            xb[slot][0] = in4[lane];
            xb[slot][1] = in4[lane + 64];
        }

        const float xs[8] = { x0.x, x0.y, x0.z, x0.w, x1.x, x1.y, x1.z, x1.w };
        float4 acc = make_float4(0.f, 0.f, 0.f, 0.f);
#pragma unroll
        for (int k = 0; k < 8; ++k) {
            acc.x += xs[k] * wreg[k].x;
            acc.y += xs[k] * wreg[k].y;
            acc.z += xs[k] * wreg[k].z;
            acc.w += xs[k] * wreg[k].w;
        }
        // reduce within each 16-lane group (VALU DPP, no cross-lane LDS traffic)
        acc.x = rowsum16(acc.x);
        acc.y = rowsum16(acc.y);
        acc.z = rowsum16(acc.z);
        acc.w = rowsum16(acc.w);
        if ((lane & 15) == 0) sPart[r0 + r][lane >> 4] = acc;
    }

    __syncthreads();

    // ---------------- Phase 1b: finish dot (4 partials), prev_h, bias, tanh, sincos ----
    // 256 threads: thread -> (row = t>>2, comp = t&3)
    {
        const int row  = tid >> 2;
        const int comp = tid & 3;
        const float* pp = (const float*)&sPart[row][0];
        float s = pp[0 * 4 + comp] + pp[1 * 4 + comp] + pp[2 * 4 + comp] + pp[3 * 4 + comp];

        const float4 ph = *(const float4*)(prev_h + (size_t)(blockBase + row) * 4);
        s += ph.x * W_enc[512 * 4 + comp];
        s += ph.y * W_enc[513 * 4 + comp];
        s += ph.z * W_enc[514 * 4 + comp];
        s += ph.w * W_enc[515 * 4 + comp];
        s += b_enc[comp];

        const float h = tanhf(s) * 1.57079632679489662f;   // half-angle
        float sn, cs;
        __sincosf(h, &sn, &cs);
        sC[row * 5 + comp] = cs;
        sS[row * 5 + comp] = sn;
    }

    __syncthreads();

    // ---------------- Phase 2: per-row 16-amplitude circuit (one thread per row) ------
    if (tid < RPB) {
        const int row = blockBase + tid;
        float cq[4], sq[4];
#pragma unroll
        for (int j = 0; j < 4; ++j) {
            cq[j] = sC[tid * 5 + j];
            sq[j] = sS[tid * 5 + j];
        }

        float ar[16], ai[16];
#pragma unroll
        for (int j = 0; j < 16; ++j) {
            float v = ((j >> 3) & 1) ? sq[0] : cq[0];
            v      *= ((j >> 2) & 1) ? sq[1] : cq[1];
            v      *= ((j >> 1) & 1) ? sq[2] : cq[2];
            v      *= ((j >> 0) & 1) ? sq[3] : cq[3];
            ar[j] = v;
            ai[j] = 0.f;
        }

#pragma unroll
        for (int l = 0; l < LQ; ++l) {
#pragma unroll
            for (int q = 0; q < NQ; ++q) {
                const float* u = &sU[(l * NQ + q) * 8];
                const float u00r = u[0], u00i = u[1], u01r = u[2], u01i = u[3];
                const float u10r = u[4], u10i = u[5], u11r = u[6], u11i = u[7];
                const int bit = 1 << (3 - q);
#pragma unroll
                for (int j = 0; j < 16; ++j) {
                    if (j & bit) continue;          // compile-time resolved
                    const int k = j | bit;
                    const float a0r = ar[j], a0i = ai[j];
                    const float a1r = ar[k], a1i = ai[k];
                    ar[j] = u00r * a0r - u00i * a0i + u01r * a1r - u01i * a1i;
                    ai[j] = u00r * a0i + u00i * a0r + u01r * a1i + u01i * a1r;
                    ar[k] = u10r * a0r - u10i * a0i + u11r * a1r - u11i * a1i;
                    ai[k] = u10r * a0i + u10i * a0r + u11r * a1i + u11i * a1r;
                }
            }
#pragma unroll
            for (int q = 0; q < NQ - 1; ++q) {      // CNOT chain
                const int cb = 1 << (3 - q), tb = 1 << (2 - q);
#pragma unroll
                for (int j = 0; j < 16; ++j) {
                    if ((j & cb) && !(j & tb)) {    // compile-time resolved
                        const int k = j | tb;
                        float t;
                        t = ar[j]; ar[j] = ar[k]; ar[k] = t;
                        t = ai[j]; ai[j] = ai[k]; ai[k] = t;
                    }
                }
            }
        }

        // PauliZ expectations
        float ev[4] = { 0.f, 0.f, 0.f, 0.f };
#pragma unroll
        for (int j = 0; j < 16; ++j) {
            const float p = ar[j] * ar[j] + ai[j] * ai[j];
#pragma unroll
            for (int q = 0; q < 4; ++q)
                ev[q] += (j & (1 << (3 - q))) ? -p : p;
        }

        // output layer
        float ob[4];
#pragma unroll
        for (int j = 0; j < 4; ++j) {
            float t = b_out[j];
#pragma unroll
            for (int q = 0; q < 4; ++q) t += ev[q] * W_out[q * 4 + j];
            ob[j] = tanhf(t);
        }
        *(float4*)(out + (size_t)row * 4) = make_float4(ob[0], ob[1], ob[2], ob[3]);
    }
}

extern "C" void kernel_launch(void* const* d_in, const int* in_sizes, int n_in,
                              void* d_out, int out_size, void* d_ws, size_t ws_size,
                              hipStream_t stream) {
    const float* inputs = (const float*)d_in[0];
    const float* prev_h = (const float*)d_in[1];
    const float* W_enc  = (const float*)d_in[2];
    const float* b_enc  = (const float*)d_in[3];
    const float* theta  = (const float*)d_in[4];
    const float* W_out  = (const float*)d_in[5];
    const float* b_out  = (const float*)d_in[6];
    float* out = (float*)d_out;

    const int B = in_sizes[0] / DQ;                 // 32768
    const int grid = (B + RPB - 1) / RPB;           // 512

    qrnn_kernel<<<grid, BLOCK, 0, stream>>>(inputs, prev_h, W_enc, b_enc, theta,
                                            W_out, b_out, out, B);
}